// Round 5
// baseline (236.710 us; speedup 1.0000x reference)
//
#include <hip/hip_runtime.h>
#include <math.h>

#define BB 8
#define CCH 256
#define C8 32
#define NN 4096
#define LOG2E 1.44269504f

typedef unsigned short us;
typedef __attribute__((ext_vector_type(8))) short bf16x8;
typedef __attribute__((ext_vector_type(4))) float f32x4;
typedef __attribute__((ext_vector_type(16))) float f32x16;

static __device__ __forceinline__ us f2bf(float f) {  // RNE
  union { float f; unsigned u; } v; v.f = f;
  unsigned r = v.u + 0x7fffu + ((v.u >> 16) & 1u);
  return (us)(r >> 16);
}
static __device__ __forceinline__ us f2bf_rhu(float f) {  // round-half-up, f>=0
  return (us)((__float_as_uint(f) + 0x8000u) >> 16);
}
template <int CTRL>
static __device__ __forceinline__ float dpp_mv(float x) {
  return __int_as_float(
      __builtin_amdgcn_update_dpp(0, __float_as_int(x), CTRL, 0xF, 0xF, false));
}
static __device__ __forceinline__ float rowsum16(float t) {  // sum within DPP row
  t += dpp_mv<0x121>(t);
  t += dpp_mv<0x122>(t);
  t += dpp_mv<0x124>(t);
  t += dpp_mv<0x128>(t);
  return t;
}

// ---------------------------------------------------------------------------
// prep_kernel: blocks 0..2047: transpose x[b][c][n] f32 -> xT[b][n][c] bf16.
//              blocks 2048..2495: weight repack (wq*LOG2E, wk im2col, wv bf16).
// ---------------------------------------------------------------------------
__global__ __launch_bounds__(256) void prep_kernel(
    const float* __restrict__ x, const float* __restrict__ wq,
    const float* __restrict__ wk, const float* __restrict__ wv,
    us* __restrict__ xT, us* __restrict__ wqc, us* __restrict__ wkc,
    us* __restrict__ wvb) {
  __shared__ __align__(16) us lt[64 * 68];
  int bid = blockIdx.x;
  int tid = threadIdx.x;
  if (bid < 2048) {
    int b = bid >> 8, cb = (bid >> 6) & 3, nb = bid & 63;
    const float* xb = x + (((size_t)(b * 256 + cb * 64)) << 12);
    int nl = tid & 63, ch = tid >> 6;
#pragma unroll
    for (int p = 0; p < 16; p++) {
      int c = p * 4 + ch;
      lt[nl * 68 + c] = f2bf(xb[((size_t)c << 12) + (nb * 64 + nl)]);
    }
    __syncthreads();
    us* xTb = xT + (((size_t)b << 12) + nb * 64) * 256 + cb * 64;
    int cw = tid & 7, nr0 = tid >> 3;
#pragma unroll
    for (int p2 = 0; p2 < 2; p2++) {
      int nr = p2 * 32 + nr0;
      uint2 lo = *(const uint2*)&lt[nr * 68 + cw * 8];
      uint2 hi = *(const uint2*)&lt[nr * 68 + cw * 8 + 4];
      *(uint4*)&xTb[(size_t)nr * 256 + cw * 8] = make_uint4(lo.x, lo.y, hi.x, hi.y);
    }
  } else {
    int idx = (bid - 2048) * 256 + tid;
    if (idx < 24576) {
      int oc = idx / 768, r = idx % 768, t = r >> 8, ic = r & 255;
      wqc[idx] = f2bf(wq[(oc * 256 + ic) * 3 + t] * LOG2E);
    } else if (idx < 49152) {
      int j = idx - 24576;
      int oc = j / 768, r = j % 768, t = r >> 8, ic = r & 255;
      wkc[j] = f2bf(wk[(oc * 256 + ic) * 3 + t]);
    } else if (idx < 114688) {
      int j = idx - 49152;
      wvb[j] = f2bf(wv[j]);
    }
  }
}

// ---------------------------------------------------------------------------
// conv_kernel: blocks 0..511: q/k convs as K=768 im2col MFMA GEMMs
//              (waves 0,1 -> q; 2,3 -> k; outputs qT/kT[b][n][oc] bf16).
//              blocks 512..1023: 1x1 v conv with SWAPPED MFMA operands so D's
//              row dim = n -> each thread packs 4 consecutive (n&15) into one
//              b64 store; every store instruction covers a contiguous 512B
//              segment of vblk[b][n>>4][oc][n&15].
// ---------------------------------------------------------------------------
__global__ __launch_bounds__(256) void conv_kernel(
    const us* __restrict__ xT, const us* __restrict__ wqc,
    const us* __restrict__ wkc, const float* __restrict__ bq,
    const float* __restrict__ bk, const us* __restrict__ wvb,
    const float* __restrict__ bv, us* __restrict__ qT, us* __restrict__ kT,
    us* __restrict__ vblk) {
  int tid = threadIdx.x, lane = tid & 63, w = tid >> 6;
  int l15 = lane & 15, quad = lane >> 4;
  if (blockIdx.x < 512) {
    int bid = blockIdx.x;
    int b = bid & 7, rt = bid >> 3;
    int n0 = rt * 64, y = rt;
    bool isq = (w < 2);
    int m0 = (w & 1) * 16;
    const us* wc = isq ? wqc : wkc;
    const us* xTb = xT + (((size_t)b << 12) * 256);
    f32x4 acc[4];
#pragma unroll
    for (int nt = 0; nt < 4; nt++) acc[nt] = (f32x4){0.f, 0.f, 0.f, 0.f};
#pragma unroll
    for (int t = 0; t < 3; t++) {
      bool killT = (!isq) && ((t == 0 && y == 0) || (t == 2 && y == 63));
      if (!killT) {
        int dn = isq ? (t - 1) : (t - 1) * 64;
#pragma unroll
        for (int k8 = 0; k8 < 8; k8++) {
          int kloc = t * 256 + k8 * 32 + quad * 8;
          bf16x8 af = *(const bf16x8*)(wc + (size_t)(m0 + l15) * 768 + kloc);
          int ic = k8 * 32 + quad * 8;
#pragma unroll
          for (int nt = 0; nt < 4; nt++) {
            int nl = nt * 16 + l15;
            int ns = n0 + nl + dn;
            ns = ns < 0 ? 0 : (ns > 4095 ? 4095 : ns);
            bf16x8 bf = *(const bf16x8*)(xTb + (size_t)ns * 256 + ic);
            if (isq && ((t == 0 && nl == 0) || (t == 2 && nl == 63)))
              bf = (bf16x8){0, 0, 0, 0, 0, 0, 0, 0};
            acc[nt] = __builtin_amdgcn_mfma_f32_16x16x32_bf16(af, bf, acc[nt], 0, 0, 0);
          }
        }
      }
    }
    const float* bias = isq ? bq : bk;
    float bsc = isq ? LOG2E : 1.0f;
    us* outp = (isq ? qT : kT) + (((size_t)b << 12) * 32);
    float b0 = bias[m0 + quad * 4 + 0] * bsc;
    float b1 = bias[m0 + quad * 4 + 1] * bsc;
    float b2 = bias[m0 + quad * 4 + 2] * bsc;
    float b3 = bias[m0 + quad * 4 + 3] * bsc;
#pragma unroll
    for (int nt = 0; nt < 4; nt++) {
      int n = n0 + nt * 16 + l15;
      unsigned lo = (unsigned)f2bf(acc[nt][0] + b0) | ((unsigned)f2bf(acc[nt][1] + b1) << 16);
      unsigned hi = (unsigned)f2bf(acc[nt][2] + b2) | ((unsigned)f2bf(acc[nt][3] + b3) << 16);
      *(uint2*)(outp + (size_t)n * 32 + m0 + quad * 4) = make_uint2(lo, hi);
    }
  } else {
    int bid = blockIdx.x - 512;
    int b = bid & 7, nt0 = bid >> 3;
    int n0 = nt0 * 64;
    const us* xTb = xT + (((size_t)b << 12) * 256);
    f32x4 acc[4][4];  // [ct][nt]; D rows = n-local, D cols = oc-local
#pragma unroll
    for (int ct = 0; ct < 4; ct++)
#pragma unroll
      for (int nt = 0; nt < 4; nt++) acc[ct][nt] = (f32x4){0.f, 0.f, 0.f, 0.f};
#pragma unroll
    for (int kk = 0; kk < 8; kk++) {
      bf16x8 bfr[4];  // A operand: A[m=n(l15)][k=ic]
#pragma unroll
      for (int nt = 0; nt < 4; nt++)
        bfr[nt] = *(const bf16x8*)(xTb + (size_t)(n0 + nt * 16 + l15) * 256 + kk * 32 + quad * 8);
#pragma unroll
      for (int ct = 0; ct < 4; ct++) {
        // B operand: B[k=ic(quad*8+u)][n=oc(l15)] = wvb[oc][ic]
        bf16x8 wf = *(const bf16x8*)(wvb + (size_t)(w * 64 + ct * 16 + l15) * 256 + kk * 32 + quad * 8);
#pragma unroll
        for (int nt = 0; nt < 4; nt++)
          acc[ct][nt] = __builtin_amdgcn_mfma_f32_16x16x32_bf16(bfr[nt], wf, acc[ct][nt], 0, 0, 0);
      }
    }
    us* vb = vblk + ((size_t)b << 20);
#pragma unroll
    for (int ct = 0; ct < 4; ct++) {
      int oc = w * 64 + ct * 16 + l15;
      float bvv = bv[oc];
#pragma unroll
      for (int nt = 0; nt < 4; nt++) {
        // thread holds n = n0+nt*16+quad*4+{0..3} at fixed oc -> one b64 store
        unsigned lo = (unsigned)f2bf(acc[ct][nt][0] + bvv) | ((unsigned)f2bf(acc[ct][nt][1] + bvv) << 16);
        unsigned hi = (unsigned)f2bf(acc[ct][nt][2] + bvv) | ((unsigned)f2bf(acc[ct][nt][3] + bvv) << 16);
        *(uint2*)(vb + ((size_t)((n0 >> 4) + nt) * 256 + oc) * 16 + quad * 4) = make_uint2(lo, hi);
      }
    }
  }
}

// ---------------------------------------------------------------------------
// Flash attention, no-max softmax, TJ=128 keys per iteration (32 iters, one
// barrier each -> 2x more MFMA per sync point than TJ=64).
// 512 thr = 8 waves. QK: wave (tw=w&3, jh=w>>2) -> 16 i x 64 j, 4 MFMA.
// P -> LDS (double-buffered). PV: wave w owns c=32w..+31, 16x mfma_32x32x16;
// V frags 1KB-coalesced from blocked layout vblk[b][j>>4][c][j&15].
// grid 512 = 8b (XCD swizzle) * 64 i-tiles; 2 blocks/CU = 16 waves/CU.
// ---------------------------------------------------------------------------
__global__ __launch_bounds__(512, 4) void attn_kernel(
    const float* __restrict__ x, const us* __restrict__ qT,
    const us* __restrict__ kT, const us* __restrict__ vblk,
    const float* __restrict__ gamma_p, float* __restrict__ out) {
  __shared__ __align__(16) us pb[2][64 * 136];  // [i][j], stride 136 (272B)
  __shared__ float lpart[2][64];

  int tid = threadIdx.x, lane = tid & 63, w = tid >> 6;
  int l15 = lane & 15, quad = lane >> 4;
  int l31 = lane & 31, h32 = lane >> 5;
  int tw = w & 3, jh = w >> 2;

  int bid = blockIdx.x;
  int b = bid & 7, i0 = (bid >> 3) * 64;

  const us* qTb = qT + (((size_t)b << 12) * 32);
  const us* kTb = kT + (((size_t)b << 12) * 32);
  const us* vbb = vblk + ((size_t)b << 20);

  bf16x8 qf = *(const bf16x8*)(qTb + (size_t)(i0 + tw * 16 + l15) * 32 + quad * 8);

  float lr[4] = {0.f, 0.f, 0.f, 0.f};
  f32x16 o[2];  // [it]: c-tile = w*32, i-tile = it*32
#pragma unroll
  for (int it = 0; it < 2; it++)
#pragma unroll
    for (int rg = 0; rg < 16; rg++) o[it][rg] = 0.f;

  int bu = 0;
  for (int jt = 0; jt < 32; jt++) {
    int j0 = jt * 128;
    // K frags: wave's 64-j half (4 x 16j)
    bf16x8 kf[4];
#pragma unroll
    for (int j2 = 0; j2 < 4; j2++)
      kf[j2] = *(const bf16x8*)(kTb + (size_t)(j0 + jh * 64 + j2 * 16 + l15) * 32 + quad * 8);
    // V frags (blocked layout: contiguous 1KB per instr), used after barrier
    bf16x8 vf[8];
#pragma unroll
    for (int ks = 0; ks < 8; ks++)
      vf[ks] = *(const bf16x8*)(vbb + ((size_t)((j0 >> 4) + ks) * 256 + w * 32 + l31) * 16 + h32 * 8);
    // ---- QK^T (pre-scaled by log2e via q) ----
    f32x4 s[4];
#pragma unroll
    for (int j2 = 0; j2 < 4; j2++)
      s[j2] = __builtin_amdgcn_mfma_f32_16x16x32_bf16(qf, kf[j2], (f32x4){0.f, 0.f, 0.f, 0.f}, 0, 0, 0);
    // ---- p = exp2(s); per-thread l partials; P -> LDS ----
    us* pw = &pb[bu][(tw * 16 + quad * 4) * 136 + jh * 64 + l15];
#pragma unroll
    for (int j2 = 0; j2 < 4; j2++)
#pragma unroll
      for (int r = 0; r < 4; r++) {
        float p = __builtin_amdgcn_exp2f(s[j2][r]);
        lr[r] += p;
        pw[r * 136 + j2 * 16] = f2bf_rhu(p);
      }
    __syncthreads();
    // ---- PV: o[it] += V[c-tile] * P[it] ----
#pragma unroll
    for (int ks = 0; ks < 8; ks++) {
      bf16x8 pf0 = *(const bf16x8*)&pb[bu][(size_t)l31 * 136 + ks * 16 + h32 * 8];
      bf16x8 pf1 = *(const bf16x8*)&pb[bu][(size_t)(32 + l31) * 136 + ks * 16 + h32 * 8];
      o[0] = __builtin_amdgcn_mfma_f32_32x32x16_bf16(vf[ks], pf0, o[0], 0, 0, 0);
      o[1] = __builtin_amdgcn_mfma_f32_32x32x16_bf16(vf[ks], pf1, o[1], 0, 0, 0);
    }
    bu ^= 1;
  }

  // ---- final l: DPP row reduce + cross-jh combine via LDS ----
  float ls[4];
#pragma unroll
  for (int r = 0; r < 4; r++) ls[r] = rowsum16(lr[r]);
  if (l15 == 0) {
#pragma unroll
    for (int r = 0; r < 4; r++) lpart[jh][tw * 16 + quad * 4 + r] = ls[r];
  }
  __syncthreads();
  float g = gamma_p[0];
  const float* xb = x + ((size_t)b << 20);
  float* ob = out + ((size_t)b << 20);
  float gl[2];
#pragma unroll
  for (int it = 0; it < 2; it++) {
    int i = it * 32 + l31;
    gl[it] = g / (lpart[0][i] + lpart[1][i]);
  }
#pragma unroll
  for (int it = 0; it < 2; it++) {
    int i = i0 + it * 32 + l31;
#pragma unroll
    for (int rg = 0; rg < 16; rg++) {
      int c = w * 32 + ((rg & 3) + 8 * (rg >> 2) + 4 * h32);
      size_t idx = ((size_t)c << 12) + i;
      ob[idx] = o[it][rg] * gl[it] + xb[idx];
    }
  }
}

// ---------------------------------------------------------------------------
extern "C" void kernel_launch(void* const* d_in, const int* in_sizes, int n_in,
                              void* d_out, int out_size, void* d_ws, size_t ws_size,
                              hipStream_t stream) {
  const float* x = (const float*)d_in[0];
  const float* wq = (const float*)d_in[1];
  const float* bq = (const float*)d_in[2];
  const float* wk = (const float*)d_in[3];
  const float* bk = (const float*)d_in[4];
  const float* wv = (const float*)d_in[5];
  const float* bv = (const float*)d_in[6];
  const float* gamma = (const float*)d_in[7];
  float* out = (float*)d_out;

  us* xT = (us*)d_ws;                 // 8,388,608
  us* qT = xT + (size_t)8388608;      // 1,048,576
  us* kT = qT + (size_t)1048576;      // 1,048,576
  us* vblk = kT + (size_t)1048576;    // 8,388,608
  us* wqc = vblk + (size_t)8388608;   // 24,576
  us* wkc = wqc + (size_t)24576;      // 24,576
  us* wvb = wkc + (size_t)24576;      // 65,536

  prep_kernel<<<2496, 256, 0, stream>>>(x, wq, wk, wv, xT, wqc, wkc, wvb);
  conv_kernel<<<1024, 256, 0, stream>>>(xT, wqc, wkc, bq, bk, wvb, bv, qT, kT, vblk);
  attn_kernel<<<512, 512, 0, stream>>>(x, qT, kT, vblk, gamma, out);
}